// Round 1
// baseline (2340.904 us; speedup 1.0000x reference)
//
#include <hip/hip_runtime.h>

#define B 8
#define N 8192
#define S 1024
#define NS 32
constexpr float BN_EPS = 1e-5f;

// ---------------------------------------------------------------------------
// K1: furthest point sampling. One block per batch; 512 threads, 16 pts/thread
// kept in registers. Exact fp32 distance math (no FMA contraction) so argmax
// selections match the NumPy reference bit-for-bit; ties -> smallest index.
// ---------------------------------------------------------------------------
#define FPS_T 512
#define FPS_PPT (N / FPS_T)  // 16
#define FPS_W (FPS_T / 64)   // 8 waves

__global__ __launch_bounds__(FPS_T) void k_fps(const float* __restrict__ xyz,
                                               float* __restrict__ new_xyz) {
#pragma clang fp contract(off)
  const int b = blockIdx.x;
  const int t = threadIdx.x;
  const float* base = xyz + (size_t)b * N * 3;
  float X[FPS_PPT], Y[FPS_PPT], Z[FPS_PPT], D[FPS_PPT];
  const int p0 = t * FPS_PPT;
  {
    // 16 points * 3 floats = 12 float4 loads, 16B-aligned (t*192 bytes)
    const float4* src = (const float4*)(base + (size_t)p0 * 3);
    float buf[FPS_PPT * 3];
#pragma unroll
    for (int i = 0; i < (FPS_PPT * 3) / 4; ++i) {
      float4 v = src[i];
      buf[4 * i + 0] = v.x; buf[4 * i + 1] = v.y;
      buf[4 * i + 2] = v.z; buf[4 * i + 3] = v.w;
    }
#pragma unroll
    for (int i = 0; i < FPS_PPT; ++i) {
      X[i] = buf[3 * i]; Y[i] = buf[3 * i + 1]; Z[i] = buf[3 * i + 2];
      D[i] = 3.4e38f;  // reference init is +inf; min(inf,d)=d and d<=3
    }
  }
  __shared__ float s_val[FPS_W];
  __shared__ int s_idx[FPS_W];
  __shared__ float s_c[3];
  float lx = base[0], ly = base[1], lz = base[2];  // start index 0
  if (t == 0) {
    float* o = new_xyz + (size_t)b * S * 3;
    o[0] = lx; o[1] = ly; o[2] = lz;  // output[0] is always point 0
  }
  for (int r = 1; r < S; ++r) {
    // exact: d = ((dx*dx)+(dy*dy))+(dz*dz), contraction off
#pragma unroll
    for (int i = 0; i < FPS_PPT; ++i) {
      float dx = X[i] - lx, dy = Y[i] - ly, dz = Z[i] - lz;
      float d = (dx * dx + dy * dy) + dz * dz;
      D[i] = fminf(D[i], d);
    }
    float m = D[0];
#pragma unroll
    for (int i = 1; i < FPS_PPT; ++i) m = fmaxf(m, D[i]);
    int li = 0;
#pragma unroll
    for (int i = FPS_PPT - 1; i >= 0; --i)
      if (D[i] == m) li = i;  // descending scan -> first (smallest) index wins
    float bv = m;
    int bi = p0 + li;
    // wave64 butterfly argmax, tie -> smaller global index
#pragma unroll
    for (int o = 32; o >= 1; o >>= 1) {
      float ov = __shfl_xor(bv, o, 64);
      int oi = __shfl_xor(bi, o, 64);
      if (ov > bv || (ov == bv && oi < bi)) { bv = ov; bi = oi; }
    }
    if ((t & 63) == 0) { s_val[t >> 6] = bv; s_idx[t >> 6] = bi; }
    __syncthreads();
    bv = s_val[0]; bi = s_idx[0];
#pragma unroll
    for (int j = 1; j < FPS_W; ++j) {
      float ov = s_val[j]; int oi = s_idx[j];
      if (ov > bv || (ov == bv && oi < bi)) { bv = ov; bi = oi; }
    }
    // owner thread broadcasts the selected point's coords from registers
    if (bi >= p0 && bi < p0 + FPS_PPT) {
      int l = bi - p0;
      float cx = 0.f, cy = 0.f, cz = 0.f;
#pragma unroll
      for (int i = 0; i < FPS_PPT; ++i)
        if (l == i) { cx = X[i]; cy = Y[i]; cz = Z[i]; }
      s_c[0] = cx; s_c[1] = cy; s_c[2] = cz;
      float* o = new_xyz + ((size_t)b * S + r) * 3;
      o[0] = cx; o[1] = cy; o[2] = cz;
    }
    __syncthreads();
    lx = s_c[0]; ly = s_c[1]; lz = s_c[2];
  }
}

// ---------------------------------------------------------------------------
// K2: ball query. One wave per center; ordered first-32-within-radius via
// ballot + popc rank; early exit once 32 found; pad with index 0.
// ---------------------------------------------------------------------------
__global__ __launch_bounds__(256) void k_ball(const float* __restrict__ xyz,
                                              const float* __restrict__ new_xyz,
                                              int* __restrict__ ball_idx) {
#pragma clang fp contract(off)
  constexpr float R2 = (float)(0.2 * 0.2);  // same double->f32 rounding as ref
  const int t = threadIdx.x;
  const int wv = (blockIdx.x << 2) + (t >> 6);  // global wave = center id
  const int lane = t & 63;
  const int b = wv >> 10;
  const float* base = xyz + (size_t)b * N * 3;
  const float* c = new_xyz + (size_t)wv * 3;
  float cx = c[0], cy = c[1], cz = c[2];
  int* out = ball_idx + (size_t)wv * NS;
  int cnt = 0;
  for (int c0 = 0; c0 < N && cnt < NS; c0 += 64) {
    int p = c0 + lane;
    float x = base[p * 3], y = base[p * 3 + 1], z = base[p * 3 + 2];
    float dx = x - cx, dy = y - cy, dz = z - cz;
    float d = (dx * dx + dy * dy) + dz * dz;
    bool v = d < R2;  // strict <, exact fp32: matches reference
    unsigned long long mk = __ballot(v);
    int rank = cnt + __popcll(mk & ((1ull << lane) - 1ull));
    if (v && rank < NS) out[rank] = p;
    cnt += (int)__popcll(mk);
  }
  if (cnt < NS)
    for (int j = cnt + lane; j < NS; j += 64) out[j] = 0;  // pad -> index 0
}

// ---------------------------------------------------------------------------
// K3: gather + 3-layer MLP (BN folded into weights) + max over nsample.
// One wave per center; lane = output channel; weights in registers;
// activations in per-wave LDS buffer read via broadcast (conflict-free).
// h2 overwrites h1 rows in place (wave-lockstep: row n fully read by all
// lanes before any lane's store of row n — enforced by data dependence).
// ---------------------------------------------------------------------------
__global__ __launch_bounds__(256) void k_mlp(
    const float* __restrict__ xyz, const int* __restrict__ ball_idx,
    const float* __restrict__ w1, const float* __restrict__ b1,
    const float* __restrict__ g1, const float* __restrict__ be1,
    const float* __restrict__ m1, const float* __restrict__ v1,
    const float* __restrict__ w2, const float* __restrict__ b2,
    const float* __restrict__ g2, const float* __restrict__ be2,
    const float* __restrict__ m2, const float* __restrict__ v2,
    const float* __restrict__ w3, const float* __restrict__ b3,
    const float* __restrict__ g3, const float* __restrict__ be3,
    const float* __restrict__ m3, const float* __restrict__ v3,
    float* __restrict__ out_feat) {
  const int t = threadIdx.x;
  const int w = t >> 6, lane = t & 63;
  const int wv = (blockIdx.x << 2) + w;
  const int b = wv >> 10, s = wv & (S - 1);
  __shared__ float sh[4][NS * 64];  // per-wave activation buffer (8KB each)
  __shared__ float sc[4][NS * 4];   // per-wave gathered coords (padded to 4)
  float* h = sh[w];
  float* cs = sc[w];
  const int* gi = ball_idx + (size_t)wv * NS;
  const float* base = xyz + (size_t)b * N * 3;
  if (lane < NS) {
    int p = gi[lane];
    cs[lane * 4 + 0] = base[p * 3 + 0];
    cs[lane * 4 + 1] = base[p * 3 + 1];
    cs[lane * 4 + 2] = base[p * 3 + 2];
  }
  __syncthreads();
  // ---- layer 1: 3 -> 64 ----
  {
    float sv = g1[lane] / sqrtf(v1[lane] + BN_EPS);
    float bb = (b1[lane] - m1[lane]) * sv + be1[lane];
    float wx = w1[lane * 3 + 0] * sv, wy = w1[lane * 3 + 1] * sv,
          wz = w1[lane * 3 + 2] * sv;
    for (int n = 0; n < NS; ++n) {
      float a = fmaf(wx, cs[n * 4 + 0],
                     fmaf(wy, cs[n * 4 + 1], fmaf(wz, cs[n * 4 + 2], bb)));
      h[n * 64 + lane] = fmaxf(a, 0.f);
    }
  }
  __syncthreads();
  // ---- layer 2: 64 -> 64 (in-place row overwrite) ----
  {
    float sv = g2[lane] / sqrtf(v2[lane] + BN_EPS);
    float bb = (b2[lane] - m2[lane]) * sv + be2[lane];
    float W[64];
#pragma unroll
    for (int k = 0; k < 64; k += 4) {
      float4 q = *(const float4*)(w2 + lane * 64 + k);
      W[k + 0] = q.x * sv; W[k + 1] = q.y * sv;
      W[k + 2] = q.z * sv; W[k + 3] = q.w * sv;
    }
    for (int n = 0; n < NS; ++n) {
      float acc = bb;
#pragma unroll
      for (int k = 0; k < 64; k += 4) {
        float4 q = *(const float4*)(h + n * 64 + k);  // broadcast read
        acc = fmaf(W[k + 0], q.x, acc);
        acc = fmaf(W[k + 1], q.y, acc);
        acc = fmaf(W[k + 2], q.z, acc);
        acc = fmaf(W[k + 3], q.w, acc);
      }
      h[n * 64 + lane] = fmaxf(acc, 0.f);
    }
  }
  __syncthreads();
  // ---- layer 3: 64 -> 128 in two channel passes, fused max over samples ----
  float of0 = 0.f, of1 = 0.f;
#pragma unroll
  for (int pass = 0; pass < 2; ++pass) {
    int cch = (pass << 6) + lane;
    float sv = g3[cch] / sqrtf(v3[cch] + BN_EPS);
    float bb = (b3[cch] - m3[cch]) * sv + be3[cch];
    float W[64];
#pragma unroll
    for (int k = 0; k < 64; k += 4) {
      float4 q = *(const float4*)(w3 + cch * 64 + k);
      W[k + 0] = q.x * sv; W[k + 1] = q.y * sv;
      W[k + 2] = q.z * sv; W[k + 3] = q.w * sv;
    }
    float mx = 0.f;  // max(relu(x)) == max(0, max(x))
    for (int n = 0; n < NS; ++n) {
      float acc = bb;
#pragma unroll
      for (int k = 0; k < 64; k += 4) {
        float4 q = *(const float4*)(h + n * 64 + k);
        acc = fmaf(W[k + 0], q.x, acc);
        acc = fmaf(W[k + 1], q.y, acc);
        acc = fmaf(W[k + 2], q.z, acc);
        acc = fmaf(W[k + 3], q.w, acc);
      }
      mx = fmaxf(mx, acc);
    }
    if (pass == 0) of0 = mx; else of1 = mx;
  }
  out_feat[((size_t)b * 128 + lane) * S + s] = of0;
  out_feat[((size_t)b * 128 + 64 + lane) * S + s] = of1;
}

// ---------------------------------------------------------------------------
extern "C" void kernel_launch(void* const* d_in, const int* in_sizes, int n_in,
                              void* d_out, int out_size, void* d_ws,
                              size_t ws_size, hipStream_t stream) {
  const float* xyz = (const float*)d_in[0];
  const float* w1 = (const float*)d_in[1];
  const float* b1 = (const float*)d_in[2];
  const float* g1 = (const float*)d_in[3];
  const float* be1 = (const float*)d_in[4];
  const float* m1 = (const float*)d_in[5];
  const float* v1 = (const float*)d_in[6];
  const float* w2 = (const float*)d_in[7];
  const float* b2 = (const float*)d_in[8];
  const float* g2 = (const float*)d_in[9];
  const float* be2 = (const float*)d_in[10];
  const float* m2 = (const float*)d_in[11];
  const float* v2 = (const float*)d_in[12];
  const float* w3 = (const float*)d_in[13];
  const float* b3 = (const float*)d_in[14];
  const float* g3 = (const float*)d_in[15];
  const float* be3 = (const float*)d_in[16];
  const float* m3 = (const float*)d_in[17];
  const float* v3 = (const float*)d_in[18];

  float* out = (float*)d_out;
  float* new_xyz = out;                        // (B, S, 3)
  float* out_feat = out + (size_t)B * S * 3;   // (B, 128, S)
  int* ball = (int*)d_ws;                      // (B, S, NS) int32, 1 MiB

  k_fps<<<B, FPS_T, 0, stream>>>(xyz, new_xyz);
  k_ball<<<(B * S) / 4, 256, 0, stream>>>(xyz, new_xyz, ball);
  k_mlp<<<(B * S) / 4, 256, 0, stream>>>(xyz, ball, w1, b1, g1, be1, m1, v1,
                                         w2, b2, g2, be2, m2, v2, w3, b3, g3,
                                         be3, m3, v3, out_feat);
}

// Round 2
// 1451.982 us; speedup vs baseline: 1.6122x; 1.6122x over previous
//
#include <hip/hip_runtime.h>

#define B 8
#define N 8192
#define S 1024
#define NS 32
constexpr float BN_EPS = 1e-5f;

typedef float v2f __attribute__((ext_vector_type(2)));

// ---------------------------------------------------------------------------
// K1: furthest point sampling. One block per batch; 512 threads, 16 pts/thread
// in registers as float2-packed triples (v_pk_* f32 math). One barrier per
// round: per-wave butterfly argmax on a packed u64 key, 8 candidates to LDS,
// ALL threads redundantly cross-reduce, then broadcast-read the winner's
// coords from global (L2 hit). Exact contract-off fp32 distance math so the
// argmax selections match the NumPy reference bit-for-bit; ties -> smallest
// index via the (8191 - idx) low word of the key.
// ---------------------------------------------------------------------------
#define FPS_T 512

__global__ __launch_bounds__(FPS_T) void k_fps(const float* __restrict__ xyz,
                                               float* __restrict__ new_xyz) {
#pragma clang fp contract(off)
  const int b = blockIdx.x;
  const int t = threadIdx.x;
  const int lane = t & 63;
  const int w = t >> 6;
  const float* base = xyz + (size_t)b * N * 3;
  v2f X[8], Y[8], Z[8], D[8];
  const int p0 = t * 16;
  {
    // 16 pts * 3 floats = 12 float4 loads, 16B-aligned (t*192 bytes)
    const float4* src = (const float4*)(base + (size_t)p0 * 3);
    float buf[48];
#pragma unroll
    for (int i = 0; i < 12; ++i) {
      float4 v = src[i];
      buf[4 * i + 0] = v.x; buf[4 * i + 1] = v.y;
      buf[4 * i + 2] = v.z; buf[4 * i + 3] = v.w;
    }
#pragma unroll
    for (int i = 0; i < 8; ++i) {
      X[i] = (v2f){buf[6 * i + 0], buf[6 * i + 3]};
      Y[i] = (v2f){buf[6 * i + 1], buf[6 * i + 4]};
      Z[i] = (v2f){buf[6 * i + 2], buf[6 * i + 5]};
      D[i] = (v2f){3.4e38f, 3.4e38f};  // ref init +inf; min(inf,d)=d, d<=3
    }
  }
  __shared__ unsigned long long s_red[2][8];
  float lx = base[0], ly = base[1], lz = base[2];  // start index 0
  if (t == 0) {
    float* o = new_xyz + (size_t)b * S * 3;
    o[0] = lx; o[1] = ly; o[2] = lz;
  }
  for (int r = 1; r < S; ++r) {
    v2f lx2 = lx, ly2 = ly, lz2 = lz;  // splat
    // exact: d = ((dx*dx)+(dy*dy))+(dz*dz), contraction off; pk ops round
    // identically to scalar per lane-half.
#pragma unroll
    for (int i = 0; i < 8; ++i) {
      v2f dx = X[i] - lx2, dy = Y[i] - ly2, dz = Z[i] - lz2;
      v2f d = (dx * dx + dy * dy) + dz * dz;
      D[i].x = fminf(D[i].x, d.x);
      D[i].y = fminf(D[i].y, d.y);
    }
    float m = fmaxf(D[0].x, D[0].y);
#pragma unroll
    for (int i = 1; i < 8; ++i) m = fmaxf(m, fmaxf(D[i].x, D[i].y));
    int li = 0;
#pragma unroll
    for (int i = 7; i >= 0; --i) {  // descending -> smallest index wins
      if (D[i].y == m) li = 2 * i + 1;
      if (D[i].x == m) li = 2 * i;
    }
    // packed key: high = f32 bits (monotone for +finite), low = 8191-idx so
    // larger key == (larger dist, then smaller index). Distinct idx -> no eq.
    unsigned long long key =
        ((unsigned long long)__float_as_uint(m) << 32) |
        (unsigned)(8191 - (p0 + li));
#pragma unroll
    for (int o = 32; o >= 1; o >>= 1) {
      unsigned long long ok =
          (unsigned long long)__shfl_xor((long long)key, o, 64);
      if (ok > key) key = ok;
    }
    if (lane == 0) s_red[r & 1][w] = key;
    __syncthreads();
    unsigned long long k0 = s_red[r & 1][0];
#pragma unroll
    for (int j = 1; j < 8; ++j) {
      unsigned long long kj = s_red[r & 1][j];
      if (kj > k0) k0 = kj;
    }
    const int bi = 8191 - (int)(unsigned)(k0 & 0xffffffffull);
    const float* cp = base + (size_t)bi * 3;  // L2-hit broadcast load
    lx = cp[0]; ly = cp[1]; lz = cp[2];
    if (t == 0) {
      float* o = new_xyz + ((size_t)b * S + r) * 3;
      o[0] = lx; o[1] = ly; o[2] = lz;
    }
  }
}

// ---------------------------------------------------------------------------
// K2: ball query. One wave per center; ordered first-32-within-radius via
// ballot + popc rank; early exit once 32 found; pad with index 0.
// ---------------------------------------------------------------------------
__global__ __launch_bounds__(256) void k_ball(const float* __restrict__ xyz,
                                              const float* __restrict__ new_xyz,
                                              int* __restrict__ ball_idx) {
#pragma clang fp contract(off)
  constexpr float R2 = (float)(0.2 * 0.2);
  const int t = threadIdx.x;
  const int wv = (blockIdx.x << 2) + (t >> 6);
  const int lane = t & 63;
  const int b = wv >> 10;
  const float* base = xyz + (size_t)b * N * 3;
  const float* c = new_xyz + (size_t)wv * 3;
  float cx = c[0], cy = c[1], cz = c[2];
  int* out = ball_idx + (size_t)wv * NS;
  int cnt = 0;
  for (int c0 = 0; c0 < N && cnt < NS; c0 += 64) {
    int p = c0 + lane;
    float x = base[p * 3], y = base[p * 3 + 1], z = base[p * 3 + 2];
    float dx = x - cx, dy = y - cy, dz = z - cz;
    float d = (dx * dx + dy * dy) + dz * dz;
    bool v = d < R2;
    unsigned long long mk = __ballot(v);
    int rank = cnt + __popcll(mk & ((1ull << lane) - 1ull));
    if (v && rank < NS) out[rank] = p;
    cnt += (int)__popcll(mk);
  }
  if (cnt < NS)
    for (int j = cnt + lane; j < NS; j += 64) out[j] = 0;
}

// ---------------------------------------------------------------------------
// K3: gather + 3-layer MLP (BN folded into weights) + max over nsample.
// One wave per center; lane = output channel; weights in registers;
// activations in per-wave LDS buffer read via broadcast.
// ---------------------------------------------------------------------------
__global__ __launch_bounds__(256) void k_mlp(
    const float* __restrict__ xyz, const int* __restrict__ ball_idx,
    const float* __restrict__ w1, const float* __restrict__ b1,
    const float* __restrict__ g1, const float* __restrict__ be1,
    const float* __restrict__ m1, const float* __restrict__ v1,
    const float* __restrict__ w2, const float* __restrict__ b2,
    const float* __restrict__ g2, const float* __restrict__ be2,
    const float* __restrict__ m2, const float* __restrict__ v2,
    const float* __restrict__ w3, const float* __restrict__ b3,
    const float* __restrict__ g3, const float* __restrict__ be3,
    const float* __restrict__ m3, const float* __restrict__ v3,
    float* __restrict__ out_feat) {
  const int t = threadIdx.x;
  const int w = t >> 6, lane = t & 63;
  const int wv = (blockIdx.x << 2) + w;
  const int b = wv >> 10, s = wv & (S - 1);
  __shared__ float sh[4][NS * 64];
  __shared__ float sc[4][NS * 4];
  float* h = sh[w];
  float* cs = sc[w];
  const int* gi = ball_idx + (size_t)wv * NS;
  const float* base = xyz + (size_t)b * N * 3;
  if (lane < NS) {
    int p = gi[lane];
    cs[lane * 4 + 0] = base[p * 3 + 0];
    cs[lane * 4 + 1] = base[p * 3 + 1];
    cs[lane * 4 + 2] = base[p * 3 + 2];
  }
  __syncthreads();
  // ---- layer 1: 3 -> 64 ----
  {
    float sv = g1[lane] / sqrtf(v1[lane] + BN_EPS);
    float bb = (b1[lane] - m1[lane]) * sv + be1[lane];
    float wx = w1[lane * 3 + 0] * sv, wy = w1[lane * 3 + 1] * sv,
          wz = w1[lane * 3 + 2] * sv;
    for (int n = 0; n < NS; ++n) {
      float a = fmaf(wx, cs[n * 4 + 0],
                     fmaf(wy, cs[n * 4 + 1], fmaf(wz, cs[n * 4 + 2], bb)));
      h[n * 64 + lane] = fmaxf(a, 0.f);
    }
  }
  __syncthreads();
  // ---- layer 2: 64 -> 64 (in-place row overwrite, wave-lockstep safe) ----
  {
    float sv = g2[lane] / sqrtf(v2[lane] + BN_EPS);
    float bb = (b2[lane] - m2[lane]) * sv + be2[lane];
    float W[64];
#pragma unroll
    for (int k = 0; k < 64; k += 4) {
      float4 q = *(const float4*)(w2 + lane * 64 + k);
      W[k + 0] = q.x * sv; W[k + 1] = q.y * sv;
      W[k + 2] = q.z * sv; W[k + 3] = q.w * sv;
    }
    for (int n = 0; n < NS; ++n) {
      float acc = bb;
#pragma unroll
      for (int k = 0; k < 64; k += 4) {
        float4 q = *(const float4*)(h + n * 64 + k);
        acc = fmaf(W[k + 0], q.x, acc);
        acc = fmaf(W[k + 1], q.y, acc);
        acc = fmaf(W[k + 2], q.z, acc);
        acc = fmaf(W[k + 3], q.w, acc);
      }
      h[n * 64 + lane] = fmaxf(acc, 0.f);
    }
  }
  __syncthreads();
  // ---- layer 3: 64 -> 128 in two channel passes, fused max over samples ----
  float of0 = 0.f, of1 = 0.f;
#pragma unroll
  for (int pass = 0; pass < 2; ++pass) {
    int cch = (pass << 6) + lane;
    float sv = g3[cch] / sqrtf(v3[cch] + BN_EPS);
    float bb = (b3[cch] - m3[cch]) * sv + be3[cch];
    float W[64];
#pragma unroll
    for (int k = 0; k < 64; k += 4) {
      float4 q = *(const float4*)(w3 + cch * 64 + k);
      W[k + 0] = q.x * sv; W[k + 1] = q.y * sv;
      W[k + 2] = q.z * sv; W[k + 3] = q.w * sv;
    }
    float mx = 0.f;  // max(relu(x)) == max(0, max(x))
    for (int n = 0; n < NS; ++n) {
      float acc = bb;
#pragma unroll
      for (int k = 0; k < 64; k += 4) {
        float4 q = *(const float4*)(h + n * 64 + k);
        acc = fmaf(W[k + 0], q.x, acc);
        acc = fmaf(W[k + 1], q.y, acc);
        acc = fmaf(W[k + 2], q.z, acc);
        acc = fmaf(W[k + 3], q.w, acc);
      }
      mx = fmaxf(mx, acc);
    }
    if (pass == 0) of0 = mx; else of1 = mx;
  }
  out_feat[((size_t)b * 128 + lane) * S + s] = of0;
  out_feat[((size_t)b * 128 + 64 + lane) * S + s] = of1;
}

// ---------------------------------------------------------------------------
extern "C" void kernel_launch(void* const* d_in, const int* in_sizes, int n_in,
                              void* d_out, int out_size, void* d_ws,
                              size_t ws_size, hipStream_t stream) {
  const float* xyz = (const float*)d_in[0];
  const float* w1 = (const float*)d_in[1];
  const float* b1 = (const float*)d_in[2];
  const float* g1 = (const float*)d_in[3];
  const float* be1 = (const float*)d_in[4];
  const float* m1 = (const float*)d_in[5];
  const float* v1 = (const float*)d_in[6];
  const float* w2 = (const float*)d_in[7];
  const float* b2 = (const float*)d_in[8];
  const float* g2 = (const float*)d_in[9];
  const float* be2 = (const float*)d_in[10];
  const float* m2 = (const float*)d_in[11];
  const float* v2 = (const float*)d_in[12];
  const float* w3 = (const float*)d_in[13];
  const float* b3 = (const float*)d_in[14];
  const float* g3 = (const float*)d_in[15];
  const float* be3 = (const float*)d_in[16];
  const float* m3 = (const float*)d_in[17];
  const float* v3 = (const float*)d_in[18];

  float* out = (float*)d_out;
  float* new_xyz = out;                        // (B, S, 3)
  float* out_feat = out + (size_t)B * S * 3;   // (B, 128, S)
  int* ball = (int*)d_ws;                      // (B, S, NS) int32, 1 MiB

  k_fps<<<B, FPS_T, 0, stream>>>(xyz, new_xyz);
  k_ball<<<(B * S) / 4, 256, 0, stream>>>(xyz, new_xyz, ball);
  k_mlp<<<(B * S) / 4, 256, 0, stream>>>(xyz, ball, w1, b1, g1, be1, m1, v1,
                                         w2, b2, g2, be2, m2, v2, w3, b3, g3,
                                         be3, m3, v3, out_feat);
}

// Round 3
// 1225.849 us; speedup vs baseline: 1.9096x; 1.1845x over previous
//
#include <hip/hip_runtime.h>

#define B 8
#define N 8192
#define S 1024
#define NS 32
constexpr float BN_EPS = 1e-5f;

typedef float v2f __attribute__((ext_vector_type(2)));

// DPP-based full-wave (64-lane) f32 max; result valid in lane 63.
__device__ __forceinline__ float wave_max_to_lane63(float x) {
  int v = __float_as_int(x);
#define DPP_MAX(ctrl)                                                     \
  v = __float_as_int(fmaxf(__int_as_float(v),                             \
      __int_as_float(__builtin_amdgcn_update_dpp(v, v, (ctrl), 0xf, 0xf, \
                                                 false))))
  DPP_MAX(0x111);  // row_shr:1
  DPP_MAX(0x112);  // row_shr:2
  DPP_MAX(0x114);  // row_shr:4
  DPP_MAX(0x118);  // row_shr:8  -> lane15/31/47/63 hold row maxima
  DPP_MAX(0x142);  // row_bcast:15 -> lane31 = rows0-1, lane63 = rows2-3
  DPP_MAX(0x143);  // row_bcast:31 -> lane63 = all 64
#undef DPP_MAX
  return __int_as_float(v);
}

// ---------------------------------------------------------------------------
// K1: furthest point sampling. One block per batch; 512 threads, 16 pts/thread
// register-resident (launch_bounds(512,2) caps occupancy target at 2 waves/EU
// so the RA doesn't spill to scratch — R2's 48-VGPR kernel was spill-bound).
// Per round: pk-f32 distance update, per-lane max over 16, DPP wave-max,
// ballot+readlane index recovery (first-set-lane == smallest index), u64-key
// cross-wave reduce via LDS (single barrier, double-buffered), winner coords
// broadcast from an LDS copy of all 8192 points. Exact contract-off fp32
// distance math -> argmax selections match the NumPy reference bit-for-bit.
// ---------------------------------------------------------------------------
#define FPS_T 512

__global__ __launch_bounds__(FPS_T, 2) void k_fps(
    const float* __restrict__ xyz, float* __restrict__ new_xyz) {
#pragma clang fp contract(off)
  extern __shared__ float s_xyz[];  // N*3 floats = 96 KB
  const int b = blockIdx.x;
  const int t = threadIdx.x;
  const int lane = t & 63;
  const int w = t >> 6;
  const float* base = xyz + (size_t)b * N * 3;
  v2f X[8], Y[8], Z[8], D[8];
  const int p0 = t * 16;
  {
    // 16 pts * 3 floats = 12 float4 loads, 16B-aligned (t*192 bytes);
    // mirrored into LDS for the per-round winner-coords broadcast.
    const float4* src = (const float4*)(base + (size_t)p0 * 3);
    float4* dst = (float4*)(s_xyz + (size_t)p0 * 3);
    float buf[48];
#pragma unroll
    for (int i = 0; i < 12; ++i) {
      float4 v = src[i];
      dst[i] = v;
      buf[4 * i + 0] = v.x; buf[4 * i + 1] = v.y;
      buf[4 * i + 2] = v.z; buf[4 * i + 3] = v.w;
    }
#pragma unroll
    for (int i = 0; i < 8; ++i) {
      X[i] = (v2f){buf[6 * i + 0], buf[6 * i + 3]};
      Y[i] = (v2f){buf[6 * i + 1], buf[6 * i + 4]};
      Z[i] = (v2f){buf[6 * i + 2], buf[6 * i + 5]};
      D[i] = (v2f){3.4e38f, 3.4e38f};  // ref init +inf; min(inf,d)=d, d<=3
    }
  }
  __shared__ unsigned long long s_red[2][8];
  float lx = base[0], ly = base[1], lz = base[2];  // start index 0
  if (t == 0) {
    float* o = new_xyz + (size_t)b * S * 3;
    o[0] = lx; o[1] = ly; o[2] = lz;
  }
  for (int r = 1; r < S; ++r) {
    v2f lx2 = lx, ly2 = ly, lz2 = lz;
    // exact: d = ((dx*dx)+(dy*dy))+(dz*dz), contraction off; pk ops round
    // identically to scalar per lane-half.
#pragma unroll
    for (int i = 0; i < 8; ++i) {
      v2f dx = X[i] - lx2, dy = Y[i] - ly2, dz = Z[i] - lz2;
      v2f d = (dx * dx + dy * dy) + dz * dz;
      D[i].x = fminf(D[i].x, d.x);
      D[i].y = fminf(D[i].y, d.y);
    }
    float m = fmaxf(D[0].x, D[0].y);
#pragma unroll
    for (int i = 1; i < 8; ++i) m = fmaxf(m, fmaxf(D[i].x, D[i].y));
    int li = 0;
#pragma unroll
    for (int i = 7; i >= 0; --i) {  // descending -> smallest index wins
      if (D[i].y == m) li = 2 * i + 1;
      if (D[i].x == m) li = 2 * i;
    }
    // wave max via DPP; index recovery via ballot (lane order == index order,
    // so first set lane == smallest point index among wave maxima).
    float wm = wave_max_to_lane63(m);
    float wavemax = __int_as_float(
        __builtin_amdgcn_readlane(__float_as_int(wm), 63));
    unsigned long long bal = __ballot(m == wavemax);
    int firstlane = (int)__builtin_ctzll(bal);
    int widx = __builtin_amdgcn_readlane(p0 + li, firstlane);
    // packed key: high = f32 bits (monotone for +finite), low = 8191-idx so
    // larger key == (larger dist, then smaller index).
    unsigned long long key =
        ((unsigned long long)__float_as_uint(wavemax) << 32) |
        (unsigned)(8191 - widx);
    if (lane == 0) s_red[r & 1][w] = key;
    __syncthreads();
    unsigned long long k0 = s_red[r & 1][0];
#pragma unroll
    for (int j = 1; j < 8; ++j) {
      unsigned long long kj = s_red[r & 1][j];
      if (kj > k0) k0 = kj;
    }
    const int bi = 8191 - (int)(unsigned)(k0 & 0xffffffffull);
    lx = s_xyz[bi * 3 + 0];  // LDS broadcast read (all lanes same addr)
    ly = s_xyz[bi * 3 + 1];
    lz = s_xyz[bi * 3 + 2];
    if (t == 0) {
      float* o = new_xyz + ((size_t)b * S + r) * 3;
      o[0] = lx; o[1] = ly; o[2] = lz;
    }
  }
}

// ---------------------------------------------------------------------------
// K2: ball query. One wave per center; ordered first-32-within-radius via
// ballot + popc rank; early exit once 32 found; pad with index 0.
// ---------------------------------------------------------------------------
__global__ __launch_bounds__(256) void k_ball(const float* __restrict__ xyz,
                                              const float* __restrict__ new_xyz,
                                              int* __restrict__ ball_idx) {
#pragma clang fp contract(off)
  constexpr float R2 = (float)(0.2 * 0.2);
  const int t = threadIdx.x;
  const int wv = (blockIdx.x << 2) + (t >> 6);
  const int lane = t & 63;
  const int b = wv >> 10;
  const float* base = xyz + (size_t)b * N * 3;
  const float* c = new_xyz + (size_t)wv * 3;
  float cx = c[0], cy = c[1], cz = c[2];
  int* out = ball_idx + (size_t)wv * NS;
  int cnt = 0;
  for (int c0 = 0; c0 < N && cnt < NS; c0 += 64) {
    int p = c0 + lane;
    float x = base[p * 3], y = base[p * 3 + 1], z = base[p * 3 + 2];
    float dx = x - cx, dy = y - cy, dz = z - cz;
    float d = (dx * dx + dy * dy) + dz * dz;
    bool v = d < R2;
    unsigned long long mk = __ballot(v);
    int rank = cnt + __popcll(mk & ((1ull << lane) - 1ull));
    if (v && rank < NS) out[rank] = p;
    cnt += (int)__popcll(mk);
  }
  if (cnt < NS)
    for (int j = cnt + lane; j < NS; j += 64) out[j] = 0;
}

// ---------------------------------------------------------------------------
// K3: gather + 3-layer MLP (BN folded into weights) + max over nsample.
// One wave per center; lane = output channel; weights in registers;
// activations in per-wave LDS buffer read via broadcast.
// ---------------------------------------------------------------------------
__global__ __launch_bounds__(256) void k_mlp(
    const float* __restrict__ xyz, const int* __restrict__ ball_idx,
    const float* __restrict__ w1, const float* __restrict__ b1,
    const float* __restrict__ g1, const float* __restrict__ be1,
    const float* __restrict__ m1, const float* __restrict__ v1,
    const float* __restrict__ w2, const float* __restrict__ b2,
    const float* __restrict__ g2, const float* __restrict__ be2,
    const float* __restrict__ m2, const float* __restrict__ v2,
    const float* __restrict__ w3, const float* __restrict__ b3,
    const float* __restrict__ g3, const float* __restrict__ be3,
    const float* __restrict__ m3, const float* __restrict__ v3,
    float* __restrict__ out_feat) {
  const int t = threadIdx.x;
  const int w = t >> 6, lane = t & 63;
  const int wv = (blockIdx.x << 2) + w;
  const int b = wv >> 10, s = wv & (S - 1);
  __shared__ float sh[4][NS * 64];
  __shared__ float sc[4][NS * 4];
  float* h = sh[w];
  float* cs = sc[w];
  const int* gi = ball_idx + (size_t)wv * NS;
  const float* base = xyz + (size_t)b * N * 3;
  if (lane < NS) {
    int p = gi[lane];
    cs[lane * 4 + 0] = base[p * 3 + 0];
    cs[lane * 4 + 1] = base[p * 3 + 1];
    cs[lane * 4 + 2] = base[p * 3 + 2];
  }
  __syncthreads();
  // ---- layer 1: 3 -> 64 ----
  {
    float sv = g1[lane] / sqrtf(v1[lane] + BN_EPS);
    float bb = (b1[lane] - m1[lane]) * sv + be1[lane];
    float wx = w1[lane * 3 + 0] * sv, wy = w1[lane * 3 + 1] * sv,
          wz = w1[lane * 3 + 2] * sv;
    for (int n = 0; n < NS; ++n) {
      float a = fmaf(wx, cs[n * 4 + 0],
                     fmaf(wy, cs[n * 4 + 1], fmaf(wz, cs[n * 4 + 2], bb)));
      h[n * 64 + lane] = fmaxf(a, 0.f);
    }
  }
  __syncthreads();
  // ---- layer 2: 64 -> 64 (in-place row overwrite, wave-lockstep safe) ----
  {
    float sv = g2[lane] / sqrtf(v2[lane] + BN_EPS);
    float bb = (b2[lane] - m2[lane]) * sv + be2[lane];
    float W[64];
#pragma unroll
    for (int k = 0; k < 64; k += 4) {
      float4 q = *(const float4*)(w2 + lane * 64 + k);
      W[k + 0] = q.x * sv; W[k + 1] = q.y * sv;
      W[k + 2] = q.z * sv; W[k + 3] = q.w * sv;
    }
    for (int n = 0; n < NS; ++n) {
      float acc = bb;
#pragma unroll
      for (int k = 0; k < 64; k += 4) {
        float4 q = *(const float4*)(h + n * 64 + k);
        acc = fmaf(W[k + 0], q.x, acc);
        acc = fmaf(W[k + 1], q.y, acc);
        acc = fmaf(W[k + 2], q.z, acc);
        acc = fmaf(W[k + 3], q.w, acc);
      }
      h[n * 64 + lane] = fmaxf(acc, 0.f);
    }
  }
  __syncthreads();
  // ---- layer 3: 64 -> 128 in two channel passes, fused max over samples ----
  float of0 = 0.f, of1 = 0.f;
#pragma unroll
  for (int pass = 0; pass < 2; ++pass) {
    int cch = (pass << 6) + lane;
    float sv = g3[cch] / sqrtf(v3[cch] + BN_EPS);
    float bb = (b3[cch] - m3[cch]) * sv + be3[cch];
    float W[64];
#pragma unroll
    for (int k = 0; k < 64; k += 4) {
      float4 q = *(const float4*)(w3 + cch * 64 + k);
      W[k + 0] = q.x * sv; W[k + 1] = q.y * sv;
      W[k + 2] = q.z * sv; W[k + 3] = q.w * sv;
    }
    float mx = 0.f;  // max(relu(x)) == max(0, max(x))
    for (int n = 0; n < NS; ++n) {
      float acc = bb;
#pragma unroll
      for (int k = 0; k < 64; k += 4) {
        float4 q = *(const float4*)(h + n * 64 + k);
        acc = fmaf(W[k + 0], q.x, acc);
        acc = fmaf(W[k + 1], q.y, acc);
        acc = fmaf(W[k + 2], q.z, acc);
        acc = fmaf(W[k + 3], q.w, acc);
      }
      mx = fmaxf(mx, acc);
    }
    if (pass == 0) of0 = mx; else of1 = mx;
  }
  out_feat[((size_t)b * 128 + lane) * S + s] = of0;
  out_feat[((size_t)b * 128 + 64 + lane) * S + s] = of1;
}

// ---------------------------------------------------------------------------
extern "C" void kernel_launch(void* const* d_in, const int* in_sizes, int n_in,
                              void* d_out, int out_size, void* d_ws,
                              size_t ws_size, hipStream_t stream) {
  const float* xyz = (const float*)d_in[0];
  const float* w1 = (const float*)d_in[1];
  const float* b1 = (const float*)d_in[2];
  const float* g1 = (const float*)d_in[3];
  const float* be1 = (const float*)d_in[4];
  const float* m1 = (const float*)d_in[5];
  const float* v1 = (const float*)d_in[6];
  const float* w2 = (const float*)d_in[7];
  const float* b2 = (const float*)d_in[8];
  const float* g2 = (const float*)d_in[9];
  const float* be2 = (const float*)d_in[10];
  const float* m2 = (const float*)d_in[11];
  const float* v2 = (const float*)d_in[12];
  const float* w3 = (const float*)d_in[13];
  const float* b3 = (const float*)d_in[14];
  const float* g3 = (const float*)d_in[15];
  const float* be3 = (const float*)d_in[16];
  const float* m3 = (const float*)d_in[17];
  const float* v3 = (const float*)d_in[18];

  float* out = (float*)d_out;
  float* new_xyz = out;                        // (B, S, 3)
  float* out_feat = out + (size_t)B * S * 3;   // (B, 128, S)
  int* ball = (int*)d_ws;                      // (B, S, NS) int32, 1 MiB

  k_fps<<<B, FPS_T, N * 3 * sizeof(float), stream>>>(xyz, new_xyz);
  k_ball<<<(B * S) / 4, 256, 0, stream>>>(xyz, new_xyz, ball);
  k_mlp<<<(B * S) / 4, 256, 0, stream>>>(xyz, ball, w1, b1, g1, be1, m1, v1,
                                         w2, b2, g2, be2, m2, v2, w3, b3, g3,
                                         be3, m3, v3, out_feat);
}

// Round 4
// 1112.987 us; speedup vs baseline: 2.1033x; 1.1014x over previous
//
#include <hip/hip_runtime.h>

#define B 8
#define N 8192
#define S 1024
#define NS 32
constexpr float BN_EPS = 1e-5f;

typedef float v2f __attribute__((ext_vector_type(2)));

// DPP-based full-wave (64-lane) f32 max; result valid in lane 63.
__device__ __forceinline__ float wave_max_to_lane63(float x) {
  int v = __float_as_int(x);
#define DPP_MAX(ctrl)                                                     \
  v = __float_as_int(fmaxf(__int_as_float(v),                             \
      __int_as_float(__builtin_amdgcn_update_dpp(v, v, (ctrl), 0xf, 0xf, \
                                                 false))))
  DPP_MAX(0x111);  // row_shr:1
  DPP_MAX(0x112);  // row_shr:2
  DPP_MAX(0x114);  // row_shr:4
  DPP_MAX(0x118);  // row_shr:8  -> lane15/31/47/63 hold row maxima
  DPP_MAX(0x142);  // row_bcast:15 -> lane31 = rows0-1, lane63 = rows2-3
  DPP_MAX(0x143);  // row_bcast:31 -> lane63 = all 64
#undef DPP_MAX
  return __int_as_float(v);
}

// ---------------------------------------------------------------------------
// K1: furthest point sampling. One block per batch; 512 threads, 16 pts/thread
// register-resident. amdgpu_waves_per_eu(2,2): max=2 removes the backend's
// high-occupancy target (R3 showed __launch_bounds__(512,2) only sets the
// MIN -> RA still targeted 10 waves/EU at 44 VGPRs and spilled X/Y/Z/D to
// scratch, ~1500 cy/round of hidden L1/L2 traffic). Grid is 8 blocks, so
// occupancy beyond 2 waves/EU buys nothing anyway.
// ---------------------------------------------------------------------------
#define FPS_T 512

__global__ void __attribute__((amdgpu_flat_work_group_size(FPS_T, FPS_T),
                               amdgpu_waves_per_eu(2, 2)))
k_fps(const float* __restrict__ xyz, float* __restrict__ new_xyz) {
#pragma clang fp contract(off)
  extern __shared__ float s_xyz[];  // N*3 floats = 96 KB
  const int b = blockIdx.x;
  const int t = threadIdx.x;
  const int lane = t & 63;
  const int w = t >> 6;
  const float* base = xyz + (size_t)b * N * 3;
  v2f X[8], Y[8], Z[8], D[8];
  const int p0 = t * 16;
  {
    // 16 pts * 3 floats = 12 float4 loads, 16B-aligned (t*192 bytes);
    // mirrored into LDS for the per-round winner-coords broadcast.
    const float4* src = (const float4*)(base + (size_t)p0 * 3);
    float4* dst = (float4*)(s_xyz + (size_t)p0 * 3);
    float buf[48];
#pragma unroll
    for (int i = 0; i < 12; ++i) {
      float4 v = src[i];
      dst[i] = v;
      buf[4 * i + 0] = v.x; buf[4 * i + 1] = v.y;
      buf[4 * i + 2] = v.z; buf[4 * i + 3] = v.w;
    }
#pragma unroll
    for (int i = 0; i < 8; ++i) {
      X[i] = (v2f){buf[6 * i + 0], buf[6 * i + 3]};
      Y[i] = (v2f){buf[6 * i + 1], buf[6 * i + 4]};
      Z[i] = (v2f){buf[6 * i + 2], buf[6 * i + 5]};
      D[i] = (v2f){3.4e38f, 3.4e38f};  // ref init +inf; min(inf,d)=d, d<=3
    }
  }
  __shared__ unsigned long long s_red[2][8];
  float lx = base[0], ly = base[1], lz = base[2];  // start index 0
  if (t == 0) {
    float* o = new_xyz + (size_t)b * S * 3;
    o[0] = lx; o[1] = ly; o[2] = lz;
  }
  for (int r = 1; r < S; ++r) {
    v2f lx2 = lx, ly2 = ly, lz2 = lz;
    // exact: d = ((dx*dx)+(dy*dy))+(dz*dz), contraction off; pk ops round
    // identically to scalar per lane-half.
#pragma unroll
    for (int i = 0; i < 8; ++i) {
      v2f dx = X[i] - lx2, dy = Y[i] - ly2, dz = Z[i] - lz2;
      v2f d = (dx * dx + dy * dy) + dz * dz;
      D[i].x = fminf(D[i].x, d.x);
      D[i].y = fminf(D[i].y, d.y);
    }
    float m = fmaxf(D[0].x, D[0].y);
#pragma unroll
    for (int i = 1; i < 8; ++i) m = fmaxf(m, fmaxf(D[i].x, D[i].y));
    int li = 0;
#pragma unroll
    for (int i = 7; i >= 0; --i) {  // descending -> smallest index wins
      if (D[i].y == m) li = 2 * i + 1;
      if (D[i].x == m) li = 2 * i;
    }
    // wave max via DPP; index recovery via ballot (lane order == index order,
    // so first set lane == smallest point index among wave maxima).
    float wm = wave_max_to_lane63(m);
    float wavemax = __int_as_float(
        __builtin_amdgcn_readlane(__float_as_int(wm), 63));
    unsigned long long bal = __ballot(m == wavemax);
    int firstlane = (int)__builtin_ctzll(bal);
    int widx = __builtin_amdgcn_readlane(p0 + li, firstlane);
    // packed key: high = f32 bits (monotone for +finite), low = 8191-idx so
    // larger key == (larger dist, then smaller index).
    unsigned long long key =
        ((unsigned long long)__float_as_uint(wavemax) << 32) |
        (unsigned)(8191 - widx);
    if (lane == 0) s_red[r & 1][w] = key;
    __syncthreads();
    unsigned long long k0 = s_red[r & 1][0];
#pragma unroll
    for (int j = 1; j < 8; ++j) {
      unsigned long long kj = s_red[r & 1][j];
      if (kj > k0) k0 = kj;
    }
    const int bi = 8191 - (int)(unsigned)(k0 & 0xffffffffull);
    lx = s_xyz[bi * 3 + 0];  // LDS broadcast read (all lanes same addr)
    ly = s_xyz[bi * 3 + 1];
    lz = s_xyz[bi * 3 + 2];
    if (t == 0) {
      float* o = new_xyz + ((size_t)b * S + r) * 3;
      o[0] = lx; o[1] = ly; o[2] = lz;
    }
  }
}

// ---------------------------------------------------------------------------
// K2: ball query. One wave per center; ordered first-32-within-radius via
// ballot + popc rank; early exit once 32 found; pad with index 0.
// ---------------------------------------------------------------------------
__global__ __launch_bounds__(256) void k_ball(const float* __restrict__ xyz,
                                              const float* __restrict__ new_xyz,
                                              int* __restrict__ ball_idx) {
#pragma clang fp contract(off)
  constexpr float R2 = (float)(0.2 * 0.2);
  const int t = threadIdx.x;
  const int wv = (blockIdx.x << 2) + (t >> 6);
  const int lane = t & 63;
  const int b = wv >> 10;
  const float* base = xyz + (size_t)b * N * 3;
  const float* c = new_xyz + (size_t)wv * 3;
  float cx = c[0], cy = c[1], cz = c[2];
  int* out = ball_idx + (size_t)wv * NS;
  int cnt = 0;
  for (int c0 = 0; c0 < N && cnt < NS; c0 += 64) {
    int p = c0 + lane;
    float x = base[p * 3], y = base[p * 3 + 1], z = base[p * 3 + 2];
    float dx = x - cx, dy = y - cy, dz = z - cz;
    float d = (dx * dx + dy * dy) + dz * dz;
    bool v = d < R2;
    unsigned long long mk = __ballot(v);
    int rank = cnt + __popcll(mk & ((1ull << lane) - 1ull));
    if (v && rank < NS) out[rank] = p;
    cnt += (int)__popcll(mk);
  }
  if (cnt < NS)
    for (int j = cnt + lane; j < NS; j += 64) out[j] = 0;
}

// ---------------------------------------------------------------------------
// K3: gather + 3-layer MLP (BN folded into weights) + max over nsample.
// One wave per center; lane = output channel; weights in registers;
// activations in per-wave LDS buffer read via broadcast (DS-pipe-bound per
// R3 model: 1536 ds_read_b128/center). Layer-3's two channel passes are now
// merged into ONE n-loop with both W3 rows (ch lane and lane+64) register-
// resident -> 1024 DS reads/center (1.5x cut). waves_per_eu(2,2) gives the
// RA the 256-VGPR budget for the ~160 live registers.
// ---------------------------------------------------------------------------
__global__ void __attribute__((amdgpu_flat_work_group_size(256, 256),
                               amdgpu_waves_per_eu(2, 2)))
k_mlp(const float* __restrict__ xyz, const int* __restrict__ ball_idx,
      const float* __restrict__ w1, const float* __restrict__ b1,
      const float* __restrict__ g1, const float* __restrict__ be1,
      const float* __restrict__ m1, const float* __restrict__ v1,
      const float* __restrict__ w2, const float* __restrict__ b2,
      const float* __restrict__ g2, const float* __restrict__ be2,
      const float* __restrict__ m2, const float* __restrict__ v2,
      const float* __restrict__ w3, const float* __restrict__ b3,
      const float* __restrict__ g3, const float* __restrict__ be3,
      const float* __restrict__ m3, const float* __restrict__ v3,
      float* __restrict__ out_feat) {
  const int t = threadIdx.x;
  const int w = t >> 6, lane = t & 63;
  const int wv = (blockIdx.x << 2) + w;
  const int b = wv >> 10, s = wv & (S - 1);
  __shared__ float sh[4][NS * 64];
  __shared__ float sc[4][NS * 4];
  float* h = sh[w];
  float* cs = sc[w];
  const int* gi = ball_idx + (size_t)wv * NS;
  const float* base = xyz + (size_t)b * N * 3;
  if (lane < NS) {
    int p = gi[lane];
    cs[lane * 4 + 0] = base[p * 3 + 0];
    cs[lane * 4 + 1] = base[p * 3 + 1];
    cs[lane * 4 + 2] = base[p * 3 + 2];
  }
  __syncthreads();
  // ---- layer 1: 3 -> 64 ----
  {
    float sv = g1[lane] / sqrtf(v1[lane] + BN_EPS);
    float bb = (b1[lane] - m1[lane]) * sv + be1[lane];
    float wx = w1[lane * 3 + 0] * sv, wy = w1[lane * 3 + 1] * sv,
          wz = w1[lane * 3 + 2] * sv;
    for (int n = 0; n < NS; ++n) {
      float a = fmaf(wx, cs[n * 4 + 0],
                     fmaf(wy, cs[n * 4 + 1], fmaf(wz, cs[n * 4 + 2], bb)));
      h[n * 64 + lane] = fmaxf(a, 0.f);
    }
  }
  __syncthreads();
  // ---- layer 2: 64 -> 64 (in-place row overwrite, wave-lockstep safe) ----
  {
    float sv = g2[lane] / sqrtf(v2[lane] + BN_EPS);
    float bb = (b2[lane] - m2[lane]) * sv + be2[lane];
    float W[64];
#pragma unroll
    for (int k = 0; k < 64; k += 4) {
      float4 q = *(const float4*)(w2 + lane * 64 + k);
      W[k + 0] = q.x * sv; W[k + 1] = q.y * sv;
      W[k + 2] = q.z * sv; W[k + 3] = q.w * sv;
    }
    for (int n = 0; n < NS; ++n) {
      float acc = bb;
#pragma unroll
      for (int k = 0; k < 64; k += 4) {
        float4 q = *(const float4*)(h + n * 64 + k);
        acc = fmaf(W[k + 0], q.x, acc);
        acc = fmaf(W[k + 1], q.y, acc);
        acc = fmaf(W[k + 2], q.z, acc);
        acc = fmaf(W[k + 3], q.w, acc);
      }
      h[n * 64 + lane] = fmaxf(acc, 0.f);
    }
  }
  __syncthreads();
  // ---- layer 3: 64 -> 128, both channel halves per n-pass, fused max ----
  float mxa = 0.f, mxb = 0.f;  // max(relu(x)) == max(0, max(x))
  {
    float sva = g3[lane] / sqrtf(v3[lane] + BN_EPS);
    float bba = (b3[lane] - m3[lane]) * sva + be3[lane];
    float svb = g3[lane + 64] / sqrtf(v3[lane + 64] + BN_EPS);
    float bbb = (b3[lane + 64] - m3[lane + 64]) * svb + be3[lane + 64];
    float Wa[64], Wb[64];
#pragma unroll
    for (int k = 0; k < 64; k += 4) {
      float4 qa = *(const float4*)(w3 + lane * 64 + k);
      Wa[k + 0] = qa.x * sva; Wa[k + 1] = qa.y * sva;
      Wa[k + 2] = qa.z * sva; Wa[k + 3] = qa.w * sva;
      float4 qb = *(const float4*)(w3 + (lane + 64) * 64 + k);
      Wb[k + 0] = qb.x * svb; Wb[k + 1] = qb.y * svb;
      Wb[k + 2] = qb.z * svb; Wb[k + 3] = qb.w * svb;
    }
    for (int n = 0; n < NS; ++n) {
      float acca = bba, accb = bbb;
#pragma unroll
      for (int k = 0; k < 64; k += 4) {
        float4 q = *(const float4*)(h + n * 64 + k);  // one read, two rows
        acca = fmaf(Wa[k + 0], q.x, acca);
        acca = fmaf(Wa[k + 1], q.y, acca);
        acca = fmaf(Wa[k + 2], q.z, acca);
        acca = fmaf(Wa[k + 3], q.w, acca);
        accb = fmaf(Wb[k + 0], q.x, accb);
        accb = fmaf(Wb[k + 1], q.y, accb);
        accb = fmaf(Wb[k + 2], q.z, accb);
        accb = fmaf(Wb[k + 3], q.w, accb);
      }
      mxa = fmaxf(mxa, acca);
      mxb = fmaxf(mxb, accb);
    }
  }
  out_feat[((size_t)b * 128 + lane) * S + s] = mxa;
  out_feat[((size_t)b * 128 + 64 + lane) * S + s] = mxb;
}

// ---------------------------------------------------------------------------
extern "C" void kernel_launch(void* const* d_in, const int* in_sizes, int n_in,
                              void* d_out, int out_size, void* d_ws,
                              size_t ws_size, hipStream_t stream) {
  const float* xyz = (const float*)d_in[0];
  const float* w1 = (const float*)d_in[1];
  const float* b1 = (const float*)d_in[2];
  const float* g1 = (const float*)d_in[3];
  const float* be1 = (const float*)d_in[4];
  const float* m1 = (const float*)d_in[5];
  const float* v1 = (const float*)d_in[6];
  const float* w2 = (const float*)d_in[7];
  const float* b2 = (const float*)d_in[8];
  const float* g2 = (const float*)d_in[9];
  const float* be2 = (const float*)d_in[10];
  const float* m2 = (const float*)d_in[11];
  const float* v2 = (const float*)d_in[12];
  const float* w3 = (const float*)d_in[13];
  const float* b3 = (const float*)d_in[14];
  const float* g3 = (const float*)d_in[15];
  const float* be3 = (const float*)d_in[16];
  const float* m3 = (const float*)d_in[17];
  const float* v3 = (const float*)d_in[18];

  float* out = (float*)d_out;
  float* new_xyz = out;                        // (B, S, 3)
  float* out_feat = out + (size_t)B * S * 3;   // (B, 128, S)
  int* ball = (int*)d_ws;                      // (B, S, NS) int32, 1 MiB

  k_fps<<<B, FPS_T, N * 3 * sizeof(float), stream>>>(xyz, new_xyz);
  k_ball<<<(B * S) / 4, 256, 0, stream>>>(xyz, new_xyz, ball);
  k_mlp<<<(B * S) / 4, 256, 0, stream>>>(xyz, ball, w1, b1, g1, be1, m1, v1,
                                         w2, b2, g2, be2, m2, v2, w3, b3, g3,
                                         be3, m3, v3, out_feat);
}